// Round 1
// baseline (729.070 us; speedup 1.0000x reference)
//
#include <hip/hip_runtime.h>
#include <hip/hip_bf16.h>

// Self_Attn (SAGAN-style) restructured:
//   G_b = X_b^T X_b                                   (768x768, symmetric)
//   energy_b = Wq G_b Wk^T + bq*(s.Wk + L*bk)^T + (s.Wq) bk^T ,  s = colsum(X_b)
//   A = softmax(energy, axis=-1)
//   out = X (A Wv)^T + (A bv) ;  neg_out = (X.wvsum + bvsum) - out
//   out1 = g*out + x ; out2 = g*neg_out + x
// Q/K/V are never materialized.

#define HD 768
#define LSEQ 4096
#define BATCH 8
#define LDSS 40  // LDS row stride in ushort (padded, 80B => 16B-aligned frag reads)

typedef unsigned short u16;
typedef __attribute__((ext_vector_type(8))) short frag_ab;
typedef __attribute__((ext_vector_type(4))) float f32x4;

struct alignas(8) U16x4 { u16 x, y, z, w; };

__device__ inline u16 f2bf(float f) {
  union { float f; unsigned u; } v; v.f = f;
  unsigned u = v.u;
  u += 0x7FFFu + ((u >> 16) & 1u);   // RNE
  return (u16)(u >> 16);
}

// ---------------- GEMM core: C = P * Q^T, 128x128 tile, 4 waves ----------------

template <typename T>
__device__ inline void stage_tile(u16* lds, const T* src, int ld, int tid) {
#pragma unroll
  for (int i = 0; i < 4; ++i) {
    int idx = tid + 256 * i;       // 0..1023
    int r = idx >> 3;              // row 0..127
    int kv = (idx & 7) * 4;        // k element offset 0..28
    if constexpr (sizeof(T) == 4) {
      float4 v = *(const float4*)(src + (size_t)r * ld + kv);
      U16x4 h;
      h.x = f2bf(v.x); h.y = f2bf(v.y); h.z = f2bf(v.z); h.w = f2bf(v.w);
      *(U16x4*)(lds + r * LDSS + kv) = h;
    } else {
      *(U16x4*)(lds + r * LDSS + kv) = *(const U16x4*)(src + (size_t)r * ld + kv);
    }
  }
}

template <typename TP, typename TQ>
__device__ inline void gemm_core(const TP* Pt, const TQ* Qt, int ldp, int ldq, int K,
                                 u16* ldsA, u16* ldsB, f32x4 (&acc)[4][4]) {
  const int tid = threadIdx.x;
  const int lane = tid & 63;
  const int wm = tid >> 7, wn = (tid >> 6) & 1;
  for (int kk = 0; kk < K; kk += 32) {
    stage_tile(ldsA, Pt + kk, ldp, tid);
    stage_tile(ldsB, Qt + kk, ldq, tid);
    __syncthreads();
    const u16* bA = ldsA + (wm * 64 + (lane & 15)) * LDSS + 8 * (lane >> 4);
    const u16* bB = ldsB + (wn * 64 + (lane & 15)) * LDSS + 8 * (lane >> 4);
    frag_ab a[4], b[4];
#pragma unroll
    for (int i = 0; i < 4; ++i) a[i] = *(const frag_ab*)(bA + i * 16 * LDSS);
#pragma unroll
    for (int j = 0; j < 4; ++j) b[j] = *(const frag_ab*)(bB + j * 16 * LDSS);
#pragma unroll
    for (int i = 0; i < 4; ++i)
#pragma unroll
      for (int j = 0; j < 4; ++j)
        acc[i][j] = __builtin_amdgcn_mfma_f32_16x16x32_bf16(a[i], b[j], acc[i][j], 0, 0, 0);
    __syncthreads();
  }
}

template <typename TP, typename TQ>
__global__ __launch_bounds__(256) void k_gemm(const TP* __restrict__ P, const TQ* __restrict__ Q,
                                              float* __restrict__ C, int ldp, int ldq, int ldc,
                                              int K, int tilesM, int tilesN, long sP, long sQ,
                                              long sC) {
  __shared__ u16 ldsA[128 * LDSS];
  __shared__ u16 ldsB[128 * LDSS];
  int bid = blockIdx.x;
  int tn = bid % tilesN;
  int tm = (bid / tilesN) % tilesM;
  int b = bid / (tilesN * tilesM);
  const TP* Pt = P + b * sP + (long)(tm * 128) * ldp;
  const TQ* Qt = Q + b * sQ + (long)(tn * 128) * ldq;
  f32x4 acc[4][4] = {};
  gemm_core(Pt, Qt, ldp, ldq, K, ldsA, ldsB, acc);
  const int lane = threadIdx.x & 63;
  const int wm = threadIdx.x >> 7, wn = (threadIdx.x >> 6) & 1;
  float* Cb = C + b * sC;
#pragma unroll
  for (int i = 0; i < 4; ++i)
#pragma unroll
    for (int j = 0; j < 4; ++j)
#pragma unroll
      for (int r = 0; r < 4; ++r) {
        int row = tm * 128 + wm * 64 + i * 16 + 4 * (lane >> 4) + r;
        int col = tn * 128 + wn * 64 + j * 16 + (lane & 15);
        Cb[(long)row * ldc + col] = acc[i][j][r];
      }
}

// energy = V1*Wk^T + bq[row]*kbp[col] + bk[col]*qb[row]
__global__ __launch_bounds__(256) void k_gemm_bias(const float* __restrict__ P,
                                                   const float* __restrict__ Q,
                                                   float* __restrict__ C, long sP, long sC,
                                                   const float* __restrict__ bq,
                                                   const float* __restrict__ bk,
                                                   const float* __restrict__ qb,
                                                   const float* __restrict__ kbp) {
  __shared__ u16 ldsA[128 * LDSS];
  __shared__ u16 ldsB[128 * LDSS];
  int bid = blockIdx.x;
  int tn = bid % 6;
  int tm = (bid / 6) % 6;
  int b = bid / 36;
  const float* Pt = P + b * sP + (long)(tm * 128) * HD;
  const float* Qt = Q + (long)(tn * 128) * HD;
  f32x4 acc[4][4] = {};
  gemm_core(Pt, Qt, HD, HD, HD, ldsA, ldsB, acc);
  const int lane = threadIdx.x & 63;
  const int wm = threadIdx.x >> 7, wn = (threadIdx.x >> 6) & 1;
  float* Cb = C + b * sC;
  const float* qbb = qb + b * HD;
  const float* kbb = kbp + b * HD;
#pragma unroll
  for (int i = 0; i < 4; ++i)
#pragma unroll
    for (int j = 0; j < 4; ++j)
#pragma unroll
      for (int r = 0; r < 4; ++r) {
        int row = tm * 128 + wm * 64 + i * 16 + 4 * (lane >> 4) + r;
        int col = tn * 128 + wn * 64 + j * 16 + (lane & 15);
        Cb[(long)row * HD + col] = acc[i][j][r] + bq[row] * kbb[col] + bk[col] * qbb[row];
      }
}

// final: out1 = g*(X M^T + c) + x ; out2 = g*((rsv+bvsum) - (X M^T + c)) + x
__global__ __launch_bounds__(256) void k_final(const float* __restrict__ x,
                                               const float* __restrict__ Mw,
                                               const float* __restrict__ cvec,
                                               const float* __restrict__ rsv,
                                               const float* __restrict__ bvs,
                                               const float* __restrict__ gamma,
                                               float* __restrict__ out) {
  __shared__ u16 ldsA[128 * LDSS];
  __shared__ u16 ldsB[128 * LDSS];
  int bid = blockIdx.x;
  int tn = bid % 6;
  int tm = (bid / 6) % 32;
  int b = bid / 192;
  const float* Pt = x + ((long)b * LSEQ + tm * 128) * HD;
  const float* Qt = Mw + (long)b * HD * HD + (long)(tn * 128) * HD;
  f32x4 acc[4][4] = {};
  gemm_core(Pt, Qt, HD, HD, HD, ldsA, ldsB, acc);
  const int lane = threadIdx.x & 63;
  const int wm = threadIdx.x >> 7, wn = (threadIdx.x >> 6) & 1;
  const float g = gamma[0];
  const float bvsum = bvs[0];
  const float* cb = cvec + b * HD;
  const float* rb = rsv + b * LSEQ;
  float* out2 = out + (long)BATCH * LSEQ * HD;
#pragma unroll
  for (int i = 0; i < 4; ++i)
#pragma unroll
    for (int j = 0; j < 4; ++j)
#pragma unroll
      for (int r = 0; r < 4; ++r) {
        int row = tm * 128 + wm * 64 + i * 16 + 4 * (lane >> 4) + r;  // l
        int col = tn * 128 + wn * 64 + j * 16 + (lane & 15);          // i
        float o = acc[i][j][r] + cb[col];
        long gi = ((long)b * LSEQ + row) * HD + col;
        float xv = x[gi];
        out[gi] = g * o + xv;
        out2[gi] = g * ((rb[row] + bvsum) - o) + xv;
      }
}

// ---------------- prep kernels ----------------

// x -> Xt (bf16 transposed [b][f][l]); s += colsums; rsv += X.wvsum rowsums
__global__ __launch_bounds__(256) void k_trans(const float* __restrict__ x, u16* __restrict__ Xt,
                                               float* __restrict__ s, float* __restrict__ rsv,
                                               const float* __restrict__ wvsum) {
  __shared__ float tile[64][65];
  __shared__ float red[4][64];
  int bid = blockIdx.x;
  int ft = bid % 12;
  int lt = (bid / 12) % 64;
  int b = bid / 768;
  int l0 = lt * 64, f0 = ft * 64;
  const float* xb = x + ((long)b * LSEQ + l0) * HD + f0;
  int t = threadIdx.x;
  int fi = t & 63, tg = t >> 6;
  float csum = 0.f;
#pragma unroll
  for (int i = 0; i < 16; ++i) {
    int li = tg * 16 + i;
    float v = xb[(long)li * HD + fi];
    tile[li][fi] = v;
    csum += v;
  }
  red[tg][fi] = csum;
  __syncthreads();
  if (tg == 0) atomicAdd(&s[b * HD + f0 + fi], red[0][fi] + red[1][fi] + red[2][fi] + red[3][fi]);
  int li2 = t & 63, fg = t >> 6;
  float rsum = 0.f;
  u16* Xtb = Xt + ((long)b * HD + f0) * LSEQ + l0;
#pragma unroll
  for (int i = 0; i < 16; ++i) {
    int fi2 = fg * 16 + i;
    float v = tile[li2][fi2];
    rsum += v * wvsum[f0 + fi2];
    Xtb[(long)fi2 * LSEQ + li2] = f2bf(v);
  }
  __syncthreads();
  red[fg][li2] = rsum;
  __syncthreads();
  if (fg == 0)
    atomicAdd(&rsv[b * LSEQ + l0 + li2], red[0][li2] + red[1][li2] + red[2][li2] + red[3][li2]);
}

// WvT[f][j] = bf16(Wv[j][f]); wvsum[f] += partials
__global__ __launch_bounds__(256) void k_wv(const float* __restrict__ Wv, u16* __restrict__ WvT,
                                            float* __restrict__ wvsum) {
  __shared__ float red[256];
  long idx = (long)blockIdx.x * 256 + threadIdx.x;
  int f = (int)(idx / HD);  // uniform per block (768 = 3*256)
  int j = (int)(idx % HD);
  float v = Wv[(long)j * HD + f];
  WvT[(long)f * HD + j] = f2bf(v);
  red[threadIdx.x] = v;
  __syncthreads();
  for (int off = 128; off > 0; off >>= 1) {
    if (threadIdx.x < off) red[threadIdx.x] += red[threadIdx.x + off];
    __syncthreads();
  }
  if (threadIdx.x == 0) atomicAdd(&wvsum[f], red[0]);
}

__global__ __launch_bounds__(256) void k_bvsum(const float* __restrict__ bv,
                                               float* __restrict__ bvs) {
  __shared__ float red[256];
  int t = threadIdx.x;
  red[t] = bv[t] + bv[t + 256] + bv[t + 512];
  __syncthreads();
  for (int off = 128; off > 0; off >>= 1) {
    if (t < off) red[t] += red[t + off];
    __syncthreads();
  }
  if (t == 0) bvs[0] = red[0];
}

// qb[b][d] = s_b . Wq[d,:] ; kbp[b][e] = s_b . Wk[e,:] + L*bk[e]
__global__ __launch_bounds__(256) void k_qbkb(const float* __restrict__ Wq,
                                              const float* __restrict__ Wk,
                                              const float* __restrict__ bk,
                                              const float* __restrict__ s, float* __restrict__ qb,
                                              float* __restrict__ kbp) {
  __shared__ float ss[HD];
  int idx = blockIdx.x * 256 + threadIdx.x;  // < 12288
  int b = idx / (2 * HD);
  int rem = idx % (2 * HD);
  int mat = rem / HD;  // uniform per block
  int d = rem % HD;
  const float* sb = s + b * HD;
  ss[threadIdx.x] = sb[threadIdx.x];
  ss[threadIdx.x + 256] = sb[threadIdx.x + 256];
  ss[threadIdx.x + 512] = sb[threadIdx.x + 512];
  __syncthreads();
  const float* Wr = (mat ? Wk : Wq) + (long)d * HD;
  float acc = 0.f;
  for (int f2 = 0; f2 < HD; ++f2) acc += ss[f2] * Wr[f2];
  if (mat)
    kbp[b * HD + d] = acc + (float)LSEQ * bk[d];
  else
    qb[b * HD + d] = acc;
}

__device__ inline float block_red(float v, int op, float* sm) {
#pragma unroll
  for (int o = 32; o > 0; o >>= 1) {
    float w = __shfl_xor(v, o);
    v = op ? (v + w) : fmaxf(v, w);
  }
  int wid = threadIdx.x >> 6;
  if ((threadIdx.x & 63) == 0) sm[wid] = v;
  __syncthreads();
  float r = op ? (sm[0] + sm[1] + sm[2] + sm[3])
              : fmaxf(fmaxf(sm[0], sm[1]), fmaxf(sm[2], sm[3]));
  __syncthreads();
  return r;
}

// row softmax (in place) + cvec[row] = A_row . bv
__global__ __launch_bounds__(256) void k_softmax(float* __restrict__ A,
                                                 const float* __restrict__ bv,
                                                 float* __restrict__ cvec) {
  __shared__ float sm[4];
  long ridx = blockIdx.x;  // b*768 + row
  float* Ar = A + ridx * HD;
  int t = threadIdx.x;
  float v0 = Ar[t], v1 = Ar[t + 256], v2 = Ar[t + 512];
  float mx = block_red(fmaxf(fmaxf(v0, v1), v2), 0, sm);
  v0 = __expf(v0 - mx);
  v1 = __expf(v1 - mx);
  v2 = __expf(v2 - mx);
  float sum = block_red(v0 + v1 + v2, 1, sm);
  float inv = 1.0f / sum;
  v0 *= inv; v1 *= inv; v2 *= inv;
  Ar[t] = v0; Ar[t + 256] = v1; Ar[t + 512] = v2;
  float cp = v0 * bv[t] + v1 * bv[t + 256] + v2 * bv[t + 512];
  cp = block_red(cp, 1, sm);
  if (t == 0) cvec[ridx] = cp;
}

extern "C" void kernel_launch(void* const* d_in, const int* in_sizes, int n_in, void* d_out,
                              int out_size, void* d_ws, size_t ws_size, hipStream_t stream) {
  const float* x = (const float*)d_in[0];
  const float* Wq = (const float*)d_in[1];
  const float* bq = (const float*)d_in[2];
  const float* Wk = (const float*)d_in[3];
  const float* bk = (const float*)d_in[4];
  const float* Wv = (const float*)d_in[5];
  const float* bv = (const float*)d_in[6];
  const float* gamma = (const float*)d_in[7];
  float* out = (float*)d_out;

  // ws layout (floats), all region sizes multiples of 4 => 16B alignment
  float* ws = (float*)d_ws;
  float* s = ws;                       // 6144
  float* rsv = s + BATCH * HD;         // 32768
  float* wvsum = rsv + BATCH * LSEQ;   // 768
  float* bvs = wvsum + HD;             // 4 (1 used)
  float* qb = bvs + 4;                 // 6144
  float* kbp = qb + BATCH * HD;        // 6144
  float* cvec = kbp + BATCH * HD;      // 6144
  u16* WvT = (u16*)(cvec + BATCH * HD);        // 589824 u16
  float* Mw = (float*)(WvT + HD * HD);         // 4718592 floats (~18.9MB); total ws ~20.4MB

  // d_out used as scratch for intermediates consumed before k_final:
  u16* Xt = (u16*)d_out;                               // 8*768*4096 bf16 (50.3MB)
  float* G = (float*)d_out + 12582912;                 // 8*768*768
  float* V1 = G + (long)BATCH * HD * HD;
  float* Abuf = V1 + (long)BATCH * HD * HD;

  size_t zbytes = (size_t)(BATCH * HD + BATCH * LSEQ + HD + 4) * sizeof(float);
  hipMemsetAsync(d_ws, 0, zbytes, stream);

  k_wv<<<2304, 256, 0, stream>>>(Wv, WvT, wvsum);
  k_bvsum<<<1, 256, 0, stream>>>(bv, bvs);
  k_trans<<<BATCH * 64 * 12, 256, 0, stream>>>(x, Xt, s, rsv, wvsum);
  // G_b = Xt_b Xt_b^T  (K = 4096)
  k_gemm<u16, u16><<<BATCH * 36, 256, 0, stream>>>(Xt, Xt, G, LSEQ, LSEQ, HD, LSEQ, 6, 6,
                                                   (long)HD * LSEQ, (long)HD * LSEQ,
                                                   (long)HD * HD);
  k_qbkb<<<48, 256, 0, stream>>>(Wq, Wk, bk, s, qb, kbp);
  // V1_b = Wq G_b   (uses G symmetry: Q = G)
  k_gemm<float, float><<<BATCH * 36, 256, 0, stream>>>(Wq, G, V1, HD, HD, HD, HD, 6, 6, 0L,
                                                       (long)HD * HD, (long)HD * HD);
  // energy_b = V1_b Wk^T + bias terms -> Abuf
  k_gemm_bias<<<BATCH * 36, 256, 0, stream>>>(V1, Wk, Abuf, (long)HD * HD, (long)HD * HD, bq, bk,
                                              qb, kbp);
  k_softmax<<<BATCH * HD, 256, 0, stream>>>(Abuf, bv, cvec);
  // M_b = A_b Wv  (Q = WvT)
  k_gemm<float, u16><<<BATCH * 36, 256, 0, stream>>>(Abuf, WvT, Mw, HD, HD, HD, HD, 6, 6,
                                                     (long)HD * HD, 0L, (long)HD * HD);
  k_final<<<BATCH * 32 * 6, 256, 0, stream>>>(x, Mw, cvec, rsv, bvs, gamma, out);
}

// Round 2
// 665.496 us; speedup vs baseline: 1.0955x; 1.0955x over previous
//
#include <hip/hip_runtime.h>
#include <hip/hip_bf16.h>

// Self_Attn (SAGAN-style) restructured:
//   G_b = X_b^T X_b (768x768, sym);  energy = Wq G Wk^T + rank-1 bias terms
//   A = softmax(energy); M = A Wv;  out = X M^T + (A bv); neg = rowsum(V) - out
// All GEMM operands are bf16 in memory; staging via global_load_lds (16B).

#define HD 768
#define LSEQ 4096
#define BATCH 8

typedef unsigned short u16;
typedef __attribute__((ext_vector_type(8))) short frag_ab;
typedef __attribute__((ext_vector_type(4))) float f32x4;
#define AS1 __attribute__((address_space(1)))
#define AS3 __attribute__((address_space(3)))

struct alignas(8) U16x4 { u16 x, y, z, w; };

__device__ inline u16 f2bf(float f) {
  union { float f; unsigned u; } v; v.f = f;
  unsigned u = v.u;
  u += 0x7FFFu + ((u >> 16) & 1u);  // RNE
  return (u16)(u >> 16);
}

// ---- staging: 128x32 u16 tile into linear LDS [128][32] ----

// bf16 source: global_load_lds, 16B/lane, wave-uniform LDS base (m97 pattern)
__device__ inline void stage_g2l(u16* lds, const u16* src, int ld, int tid) {
  int w = tid >> 6, l = tid & 63;
  int r0 = w * 32 + (l >> 2);
  int kc = (l & 3) * 8;
  const u16* g0 = src + (size_t)r0 * ld + kc;
  const u16* g1 = g0 + (size_t)16 * ld;
  u16* l0 = lds + w * 1024;        // bytes w*2048
  u16* l1 = lds + w * 1024 + 512;  // +1024 B
  __builtin_amdgcn_global_load_lds((const AS1 void*)g0, (AS3 void*)l0, 16, 0, 0);
  __builtin_amdgcn_global_load_lds((const AS1 void*)g1, (AS3 void*)l1, 16, 0, 0);
}

// fp32 source: convert + ds_write (fallback path only)
__device__ inline void stage_cvt(u16* lds, const float* src, int ld, int tid) {
#pragma unroll
  for (int i = 0; i < 4; ++i) {
    int idx = tid + 256 * i;
    int r = idx >> 3;
    int kv = (idx & 7) * 4;
    float4 v = *(const float4*)(src + (size_t)r * ld + kv);
    U16x4 h;
    h.x = f2bf(v.x); h.y = f2bf(v.y); h.z = f2bf(v.z); h.w = f2bf(v.w);
    *(U16x4*)(lds + r * 32 + kv) = h;
  }
}

// ---- GEMM core: C = P * Q^T, 128x128 tile, 4 waves, BK=32 ----
template <typename TP>
__device__ inline void gemm_core(const TP* Pt, const u16* Qt, int ldp, int ldq, int K,
                                 u16* ldsA, u16* ldsB, f32x4 (&acc)[4][4]) {
  const int tid = threadIdx.x;
  const int lane = tid & 63;
  const int wm = tid >> 7, wn = (tid >> 6) & 1;
  for (int kk = 0; kk < K; kk += 32) {
    if constexpr (sizeof(TP) == 2)
      stage_g2l(ldsA, (const u16*)Pt + kk, ldp, tid);
    else
      stage_cvt(ldsA, (const float*)Pt + kk, ldp, tid);
    stage_g2l(ldsB, Qt + kk, ldq, tid);
    __syncthreads();
    const u16* bA = ldsA + (wm * 64 + (lane & 15)) * 32 + 8 * (lane >> 4);
    const u16* bB = ldsB + (wn * 64 + (lane & 15)) * 32 + 8 * (lane >> 4);
    frag_ab a[4], b[4];
#pragma unroll
    for (int i = 0; i < 4; ++i) a[i] = *(const frag_ab*)(bA + i * 16 * 32);
#pragma unroll
    for (int j = 0; j < 4; ++j) b[j] = *(const frag_ab*)(bB + j * 16 * 32);
#pragma unroll
    for (int i = 0; i < 4; ++i)
#pragma unroll
      for (int j = 0; j < 4; ++j)
        acc[i][j] = __builtin_amdgcn_mfma_f32_16x16x32_bf16(a[i], b[j], acc[i][j], 0, 0, 0);
    __syncthreads();
  }
}

// plain C = P*Q^T, CT = float or u16(bf16) output
template <typename CT>
__global__ __launch_bounds__(256) void k_gemm_c(const u16* __restrict__ P,
                                                const u16* __restrict__ Q, CT* __restrict__ C,
                                                int ldp, int ldq, int ldc, int K, int tilesM,
                                                int tilesN, long sP, long sQ, long sC) {
  __shared__ u16 ldsA[128 * 32];
  __shared__ u16 ldsB[128 * 32];
  int bid = blockIdx.x;
  int tn = bid % tilesN;
  int tm = (bid / tilesN) % tilesM;
  int b = bid / (tilesN * tilesM);
  const u16* Pt = P + b * sP + (long)(tm * 128) * ldp;
  const u16* Qt = Q + b * sQ + (long)(tn * 128) * ldq;
  f32x4 acc[4][4] = {};
  gemm_core(Pt, Qt, ldp, ldq, K, ldsA, ldsB, acc);
  const int lane = threadIdx.x & 63;
  const int wm = threadIdx.x >> 7, wn = (threadIdx.x >> 6) & 1;
  CT* Cb = C + b * sC;
#pragma unroll
  for (int i = 0; i < 4; ++i)
#pragma unroll
    for (int j = 0; j < 4; ++j)
#pragma unroll
      for (int r = 0; r < 4; ++r) {
        int row = tm * 128 + wm * 64 + i * 16 + 4 * (lane >> 4) + r;
        int col = tn * 128 + wn * 64 + j * 16 + (lane & 15);
        if constexpr (sizeof(CT) == 2)
          Cb[(long)row * ldc + col] = f2bf(acc[i][j][r]);
        else
          Cb[(long)row * ldc + col] = acc[i][j][r];
      }
}

// energy = V1h*Wkh^T + bq[row]*kbp[col] + bk[col]*qb[row]  (fp32 out)
__global__ __launch_bounds__(256) void k_gemm_bias(const u16* __restrict__ P,
                                                   const u16* __restrict__ Q,
                                                   float* __restrict__ C, long sP, long sC,
                                                   const float* __restrict__ bq,
                                                   const float* __restrict__ bk,
                                                   const float* __restrict__ qb,
                                                   const float* __restrict__ kbp) {
  __shared__ u16 ldsA[128 * 32];
  __shared__ u16 ldsB[128 * 32];
  int bid = blockIdx.x;
  int tn = bid % 6;
  int tm = (bid / 6) % 6;
  int b = bid / 36;
  const u16* Pt = P + b * sP + (long)(tm * 128) * HD;
  const u16* Qt = Q + (long)(tn * 128) * HD;
  f32x4 acc[4][4] = {};
  gemm_core(Pt, Qt, HD, HD, HD, ldsA, ldsB, acc);
  const int lane = threadIdx.x & 63;
  const int wm = threadIdx.x >> 7, wn = (threadIdx.x >> 6) & 1;
  float* Cb = C + b * sC;
  const float* qbb = qb + b * HD;
  const float* kbb = kbp + b * HD;
#pragma unroll
  for (int i = 0; i < 4; ++i)
#pragma unroll
    for (int j = 0; j < 4; ++j)
#pragma unroll
      for (int r = 0; r < 4; ++r) {
        int row = tm * 128 + wm * 64 + i * 16 + 4 * (lane >> 4) + r;
        int col = tn * 128 + wn * 64 + j * 16 + (lane & 15);
        Cb[(long)row * HD + col] = acc[i][j][r] + bq[row] * kbb[col] + bk[col] * qbb[row];
      }
}

// final: o = X M^T + c;  out1 = g*o + x ; out2 = g*((rsv+bvsum)-o) + x
template <typename TP>
__global__ __launch_bounds__(256) void k_final(const TP* __restrict__ XP,
                                               const float* __restrict__ x,
                                               const u16* __restrict__ Mw,
                                               const float* __restrict__ cvec,
                                               const float* __restrict__ rsv,
                                               const float* __restrict__ bvs,
                                               const float* __restrict__ gamma,
                                               float* __restrict__ out) {
  __shared__ u16 ldsA[128 * 32];
  __shared__ u16 ldsB[128 * 32];
  int bid = blockIdx.x;
  int tn = bid % 6;
  int tm = (bid / 6) % 32;
  int b = bid / 192;
  const TP* Pt = XP + ((long)b * LSEQ + tm * 128) * HD;
  const u16* Qt = Mw + (long)b * HD * HD + (long)(tn * 128) * HD;
  f32x4 acc[4][4] = {};
  gemm_core(Pt, Qt, HD, HD, HD, ldsA, ldsB, acc);
  const int lane = threadIdx.x & 63;
  const int wm = threadIdx.x >> 7, wn = (threadIdx.x >> 6) & 1;
  const float g = gamma[0];
  const float bvsum = bvs[0];
  const float* cb = cvec + b * HD;
  const float* rb = rsv + b * LSEQ;
  float* out2 = out + (long)BATCH * LSEQ * HD;
#pragma unroll
  for (int i = 0; i < 4; ++i)
#pragma unroll
    for (int j = 0; j < 4; ++j)
#pragma unroll
      for (int r = 0; r < 4; ++r) {
        int row = tm * 128 + wm * 64 + i * 16 + 4 * (lane >> 4) + r;  // l
        int col = tn * 128 + wn * 64 + j * 16 + (lane & 15);          // i
        float o = acc[i][j][r] + cb[col];
        long gi = ((long)b * LSEQ + row) * HD + col;
        float xv = x[gi];
        out[gi] = g * o + xv;
        out2[gi] = g * ((rb[row] + bvsum) - o) + xv;
      }
}

// ---------------- prep kernels ----------------

// x -> Xt (bf16 [b][f][l]) [+ Xbf bf16 [b][l][f]]; s += colsums; rsv += X.wvsum
template <int WX>
__global__ __launch_bounds__(256) void k_trans(const float* __restrict__ x, u16* __restrict__ Xt,
                                               u16* __restrict__ Xbf, float* __restrict__ s,
                                               float* __restrict__ rsv,
                                               const float* __restrict__ wvsum) {
  __shared__ float tile[64][65];
  __shared__ float red[4][64];
  int bid = blockIdx.x;
  int ft = bid % 12;
  int lt = (bid / 12) % 64;
  int b = bid / 768;
  int l0 = lt * 64, f0 = ft * 64;
  const float* xb = x + ((long)b * LSEQ + l0) * HD + f0;
  int t = threadIdx.x;
  int fi = t & 63, tg = t >> 6;
  float csum = 0.f;
#pragma unroll
  for (int i = 0; i < 16; ++i) {
    int li = tg * 16 + i;
    float v = xb[(long)li * HD + fi];
    tile[li][fi] = v;
    csum += v;
    if constexpr (WX) Xbf[((long)b * LSEQ + l0 + li) * HD + f0 + fi] = f2bf(v);
  }
  red[tg][fi] = csum;
  __syncthreads();
  if (tg == 0) atomicAdd(&s[b * HD + f0 + fi], red[0][fi] + red[1][fi] + red[2][fi] + red[3][fi]);
  int li2 = t & 63, fg = t >> 6;
  float rsum = 0.f;
  u16* Xtb = Xt + ((long)b * HD + f0) * LSEQ + l0;
#pragma unroll
  for (int i = 0; i < 16; ++i) {
    int fi2 = fg * 16 + i;
    float v = tile[li2][fi2];
    rsum += v * wvsum[f0 + fi2];
    Xtb[(long)fi2 * LSEQ + li2] = f2bf(v);
  }
  __syncthreads();
  red[fg][li2] = rsum;
  __syncthreads();
  if (fg == 0)
    atomicAdd(&rsv[b * LSEQ + l0 + li2], red[0][li2] + red[1][li2] + red[2][li2] + red[3][li2]);
}

// WvT[f][j] = bf16(Wv[j][f]); wvsum[f] += colsum partials
__global__ __launch_bounds__(256) void k_wv(const float* __restrict__ Wv, u16* __restrict__ WvT,
                                            float* __restrict__ wvsum) {
  __shared__ float red[256];
  long idx = (long)blockIdx.x * 256 + threadIdx.x;
  int f = (int)(idx / HD);  // uniform per block
  int j = (int)(idx % HD);
  float v = Wv[(long)j * HD + f];
  WvT[(long)f * HD + j] = f2bf(v);
  red[threadIdx.x] = v;
  __syncthreads();
  for (int off = 128; off > 0; off >>= 1) {
    if (threadIdx.x < off) red[threadIdx.x] += red[threadIdx.x + off];
    __syncthreads();
  }
  if (threadIdx.x == 0) atomicAdd(&wvsum[f], red[0]);
}

// Wq, Wk -> bf16
__global__ __launch_bounds__(256) void k_cvtw(const float* __restrict__ Wq,
                                              const float* __restrict__ Wk,
                                              u16* __restrict__ Wqh, u16* __restrict__ Wkh) {
  int idx = blockIdx.x * 256 + threadIdx.x;  // < 1179648
  if (idx < HD * HD)
    Wqh[idx] = f2bf(Wq[idx]);
  else
    Wkh[idx - HD * HD] = f2bf(Wk[idx - HD * HD]);
}

__global__ __launch_bounds__(256) void k_bvsum(const float* __restrict__ bv,
                                               float* __restrict__ bvs) {
  __shared__ float red[256];
  int t = threadIdx.x;
  red[t] = bv[t] + bv[t + 256] + bv[t + 512];
  __syncthreads();
  for (int off = 128; off > 0; off >>= 1) {
    if (t < off) red[t] += red[t + off];
    __syncthreads();
  }
  if (t == 0) bvs[0] = red[0];
}

// qb[b][d] = s_b . Wq[d,:] ; kbp[b][e] = s_b . Wk[e,:] + L*bk[e]
__global__ __launch_bounds__(256) void k_qbkb(const float* __restrict__ Wq,
                                              const float* __restrict__ Wk,
                                              const float* __restrict__ bk,
                                              const float* __restrict__ s, float* __restrict__ qb,
                                              float* __restrict__ kbp) {
  __shared__ float ss[HD];
  int idx = blockIdx.x * 256 + threadIdx.x;  // < 12288
  int b = idx / (2 * HD);
  int rem = idx % (2 * HD);
  int mat = rem / HD;  // uniform per block
  int d = rem % HD;
  const float* sb = s + b * HD;
  ss[threadIdx.x] = sb[threadIdx.x];
  ss[threadIdx.x + 256] = sb[threadIdx.x + 256];
  ss[threadIdx.x + 512] = sb[threadIdx.x + 512];
  __syncthreads();
  const float* Wr = (mat ? Wk : Wq) + (long)d * HD;
  float acc = 0.f;
  for (int f2 = 0; f2 < HD; f2 += 4) {
    float4 w4 = *(const float4*)(Wr + f2);
    acc += ss[f2] * w4.x + ss[f2 + 1] * w4.y + ss[f2 + 2] * w4.z + ss[f2 + 3] * w4.w;
  }
  if (mat)
    kbp[b * HD + d] = acc + (float)LSEQ * bk[d];
  else
    qb[b * HD + d] = acc;
}

__device__ inline float block_red(float v, int op, float* sm) {
#pragma unroll
  for (int o = 32; o > 0; o >>= 1) {
    float w = __shfl_xor(v, o);
    v = op ? (v + w) : fmaxf(v, w);
  }
  int wid = threadIdx.x >> 6;
  if ((threadIdx.x & 63) == 0) sm[wid] = v;
  __syncthreads();
  float r = op ? (sm[0] + sm[1] + sm[2] + sm[3])
              : fmaxf(fmaxf(sm[0], sm[1]), fmaxf(sm[2], sm[3]));
  __syncthreads();
  return r;
}

// row softmax: energy fp32 -> Ah bf16 ; cvec[row] = A_row . bv
__global__ __launch_bounds__(256) void k_softmax(const float* __restrict__ E,
                                                 const float* __restrict__ bv,
                                                 u16* __restrict__ Ah, float* __restrict__ cvec) {
  __shared__ float sm[4];
  long ridx = blockIdx.x;  // b*768 + row
  const float* Er = E + ridx * HD;
  int t = threadIdx.x;
  float v0 = Er[t], v1 = Er[t + 256], v2 = Er[t + 512];
  float mx = block_red(fmaxf(fmaxf(v0, v1), v2), 0, sm);
  v0 = __expf(v0 - mx);
  v1 = __expf(v1 - mx);
  v2 = __expf(v2 - mx);
  float sum = block_red(v0 + v1 + v2, 1, sm);
  float inv = 1.0f / sum;
  v0 *= inv; v1 *= inv; v2 *= inv;
  u16* Ar = Ah + ridx * HD;
  Ar[t] = f2bf(v0); Ar[t + 256] = f2bf(v1); Ar[t + 512] = f2bf(v2);
  float cp = v0 * bv[t] + v1 * bv[t + 256] + v2 * bv[t + 512];
  cp = block_red(cp, 1, sm);
  if (t == 0) cvec[ridx] = cp;
}

extern "C" void kernel_launch(void* const* d_in, const int* in_sizes, int n_in, void* d_out,
                              int out_size, void* d_ws, size_t ws_size, hipStream_t stream) {
  const float* x = (const float*)d_in[0];
  const float* Wq = (const float*)d_in[1];
  const float* bq = (const float*)d_in[2];
  const float* Wk = (const float*)d_in[3];
  const float* bk = (const float*)d_in[4];
  const float* Wv = (const float*)d_in[5];
  const float* bv = (const float*)d_in[6];
  const float* gamma = (const float*)d_in[7];
  float* out = (float*)d_out;

  // ws layout (floats); all offsets multiple of 4 floats => 16B aligned
  float* ws = (float*)d_ws;
  float* s = ws;                      // 6144
  float* rsv = s + BATCH * HD;        // 32768
  float* wvsum = rsv + BATCH * LSEQ;  // 768
  float* bvs = wvsum + HD;            // 8
  float* qb = bvs + 8;                // 6144
  float* kbp = qb + BATCH * HD;       // 6144
  float* cvec = kbp + BATCH * HD;     // 6144
  u16* Mh = (u16*)(cvec + BATCH * HD);           // 4718592 u16 (= 2359296 f)
  u16* Xbf = (u16*)((float*)Mh + 2359296);       // 25165824 u16 (= 12582912 f)
  size_t ws_need = (size_t)(6144 + 32768 + 768 + 8 + 3 * 6144 + 2359296 + 12582912) * 4;
  bool fast = ws_size >= ws_need;

  // d_out scratch (consumed before k_final writes outputs)
  u16* Xt = (u16*)d_out;                          // 25165824 u16
  float* Abuf = (float*)d_out + 12582912;         // 4718592 f32
  u16* Gh = (u16*)((float*)d_out + 17301504);     // 4718592 u16
  u16* V1h = (u16*)((float*)d_out + 19660800);    // 4718592 u16
  u16* Ah = (u16*)((float*)d_out + 22020096);     // 4718592 u16
  u16* WvT = (u16*)((float*)d_out + 24379392);    // 589824 u16
  u16* Wqh = (u16*)((float*)d_out + 24674304);    // 589824 u16
  u16* Wkh = (u16*)((float*)d_out + 24969216);    // 589824 u16

  size_t zbytes = (size_t)(6144 + 32768 + 768 + 8) * sizeof(float);
  hipMemsetAsync(d_ws, 0, zbytes, stream);

  k_cvtw<<<4608, 256, 0, stream>>>(Wq, Wk, Wqh, Wkh);
  k_wv<<<2304, 256, 0, stream>>>(Wv, WvT, wvsum);
  k_bvsum<<<1, 256, 0, stream>>>(bv, bvs);
  if (fast)
    k_trans<1><<<BATCH * 64 * 12, 256, 0, stream>>>(x, Xt, Xbf, s, rsv, wvsum);
  else
    k_trans<0><<<BATCH * 64 * 12, 256, 0, stream>>>(x, Xt, nullptr, s, rsv, wvsum);
  // G_b = Xt_b Xt_b^T (K=4096) -> bf16
  k_gemm_c<u16><<<BATCH * 36, 256, 0, stream>>>(Xt, Xt, Gh, LSEQ, LSEQ, HD, LSEQ, 6, 6,
                                                (long)HD * LSEQ, (long)HD * LSEQ, (long)HD * HD);
  k_qbkb<<<48, 256, 0, stream>>>(Wq, Wk, bk, s, qb, kbp);
  // V1_b = Wq G_b (G symmetric -> Q = Gh)
  k_gemm_c<u16><<<BATCH * 36, 256, 0, stream>>>(Wqh, Gh, V1h, HD, HD, HD, HD, 6, 6, 0L,
                                                (long)HD * HD, (long)HD * HD);
  // energy_b = V1_b Wk^T + bias -> Abuf (fp32)
  k_gemm_bias<<<BATCH * 36, 256, 0, stream>>>(V1h, Wkh, Abuf, (long)HD * HD, (long)HD * HD, bq,
                                              bk, qb, kbp);
  k_softmax<<<BATCH * HD, 256, 0, stream>>>(Abuf, bv, Ah, cvec);
  // M_b = A_b Wv  (Q = WvT)
  k_gemm_c<u16><<<BATCH * 36, 256, 0, stream>>>(Ah, WvT, Mh, HD, HD, HD, HD, 6, 6,
                                                (long)HD * HD, 0L, (long)HD * HD);
  if (fast)
    k_final<u16><<<BATCH * 32 * 6, 256, 0, stream>>>(Xbf, x, Mh, cvec, rsv, bvs, gamma, out);
  else
    k_final<float><<<BATCH * 32 * 6, 256, 0, stream>>>(x, x, Mh, cvec, rsv, bvs, gamma, out);
}